// Round 16
// baseline (219.653 us; speedup 1.0000x reference)
//
#include <hip/hip_runtime.h>
#include <cstdint>
#include <cstddef>

constexpr int V   = 128001;
constexpr int D   = 128;
constexpr int S   = 200;
constexpr int E   = 409600;
constexpr int G4  = 512;
constexpr int CAP = 8192;

typedef _Float16 half8 __attribute__((ext_vector_type(8)));
typedef float    f32x4 __attribute__((ext_vector_type(4)));

__device__ __forceinline__ float rcp_fast(float x) {
    float r;
    asm volatile("v_rcp_f32 %0, %1" : "=v"(r) : "v"(x));
    return r;
}
__device__ __forceinline__ float sigmoid_fast(float x) {
    x = fminf(fmaxf(x, -15.f), 15.f);
    return rcp_fast(1.f + __expf(-x));
}
__device__ __forceinline__ float tanh_fast(float x) {
    x = fminf(fmaxf(x, -7.5f), 7.5f);
    float e = __expf(2.f * x);
    return (e - 1.f) * rcp_fast(e + 1.f);
}
__device__ __forceinline__ half8 cvt_h8(float4 f0, float4 f1) {
    half8 h = {(_Float16)f0.x, (_Float16)f0.y, (_Float16)f0.z, (_Float16)f0.w,
               (_Float16)f1.x, (_Float16)f1.y, (_Float16)f1.z, (_Float16)f1.w};
    return h;
}
// split-fp16: hi = fp16(x), lo = fp16(x - hi); hi+lo carries ~22 mantissa bits
__device__ __forceinline__ void split_h8(float4 f0, float4 f1, half8& hi, half8& lo) {
    hi = cvt_h8(f0, f1);
    half8 l = {(_Float16)(f0.x - (float)hi[0]), (_Float16)(f0.y - (float)hi[1]),
               (_Float16)(f0.z - (float)hi[2]), (_Float16)(f0.w - (float)hi[3]),
               (_Float16)(f1.x - (float)hi[4]), (_Float16)(f1.y - (float)hi[5]),
               (_Float16)(f1.z - (float)hi[6]), (_Float16)(f1.w - (float)hi[7])};
    lo = l;
}

// ---------------- degree pass + edge filter (dst % 200 == 199) ----------------
__global__ void k_deg_filter(const int* __restrict__ src, const int* __restrict__ dst,
                             int* __restrict__ deg_out, int* __restrict__ degr,
                             int* __restrict__ ecount, int2* __restrict__ elist)
{
    int e = blockIdx.x * blockDim.x + threadIdx.x;
    if (e >= E) return;
    int s = src[e], d = dst[e];
    atomicAdd(&deg_out[s], 1);
    if (d % S == S - 1) {
        int b = d / S;
        atomicAdd(&degr[b], 1);
        int p = atomicAdd(ecount, 1);
        if (p < CAP) elist[p] = make_int2(s, b);
    }
}

// ---------------- aggregate filtered edges ----------------
__global__ void k_agg(const int2* __restrict__ elist, const int* __restrict__ ecount,
                      const int* __restrict__ gnodes, const float* __restrict__ emb,
                      const int* __restrict__ deg_out, float* __restrict__ agg64)
{
    int cnt = *ecount; if (cnt > CAP) cnt = CAP;
    int idx = blockIdx.x * 2 + (threadIdx.x >> 7);
    int d   = threadIdx.x & 127;
    if (idx >= cnt) return;
    int2 eb = elist[idx];
    int s = eb.x, b = eb.y;
    int dg = deg_out[s];
    float ns = (dg > 0) ? rsqrtf((float)dg) : 0.f;
    float v = emb[(size_t)gnodes[s] * D + d] * ns;
    atomicAdd(&agg64[b * D + d], v);
}

// ---------------- h64 = relu((agg64 * n_dst) @ gW + gb), 64x128 ----------------
__global__ __launch_bounds__(512) void k_h64(const float* __restrict__ agg64,
                                             const int* __restrict__ degr,
                                             const float* __restrict__ gW,
                                             const float* __restrict__ gb,
                                             float* __restrict__ h64)
{
    __shared__ float a[64][128];
    for (int i = threadIdx.x; i < 64 * 128; i += blockDim.x) {
        int b = i >> 7;
        int dg = degr[b];
        float nd = (dg > 0) ? rsqrtf((float)dg) : 0.f;
        a[b][i & 127] = agg64[i] * nd;
    }
    __syncthreads();
    int j  = threadIdx.x & 127;
    int bg = threadIdx.x >> 7;
    float acc[16];
    float bias = gb[j];
#pragma unroll
    for (int ii = 0; ii < 16; ++ii) acc[ii] = bias;
    for (int k = 0; k < 128; ++k) {
        float w = gW[k * 128 + j];
#pragma unroll
        for (int ii = 0; ii < 16; ++ii) acc[ii] = fmaf(a[bg * 16 + ii][k], w, acc[ii]);
    }
#pragma unroll
    for (int ii = 0; ii < 16; ++ii)
        h64[(bg * 16 + ii) * 128 + j] = fmaxf(acc[ii], 0.f);
}

// ---------------- Gpre[t][u] = A[t] . Wih[u] + b1[u] + b2[u]  (64 x 512) ----------------
__global__ __launch_bounds__(256) void k_gemmG(const float* __restrict__ A,
                                               const float* __restrict__ Wih,
                                               const float* __restrict__ b1,
                                               const float* __restrict__ b2,
                                               float* __restrict__ Gpre)
{
    __shared__ float a[16][128];
    int tq = blockIdx.x >> 1;
    int ub = blockIdx.x & 1;
    for (int i = threadIdx.x; i < 16 * 128; i += 256)
        a[i >> 7][i & 127] = A[(tq * 16 + (i >> 7)) * 128 + (i & 127)];
    __syncthreads();
    int u = ub * 256 + threadIdx.x;
    float bias = b1[u] + b2[u];
    float acc[16];
#pragma unroll
    for (int t = 0; t < 16; ++t) acc[t] = bias;
    const float4* wr = reinterpret_cast<const float4*>(Wih + (size_t)u * 128);
    for (int k4 = 0; k4 < 32; ++k4) {
        float4 w4 = wr[k4];
#pragma unroll
        for (int t = 0; t < 16; ++t) {
            float4 av = *reinterpret_cast<const float4*>(&a[t][k4 * 4]);
            acc[t] += fmaf(w4.x, av.x, fmaf(w4.y, av.y, fmaf(w4.z, av.z, w4.w * av.w)));
        }
    }
#pragma unroll
    for (int t = 0; t < 16; ++t) Gpre[(tq * 16 + t) * G4 + u] = acc[t];
}

// ---------------- single-row LSTM via MFMA; Gpre staged in LDS ----------------
// R15 post-mortem: step period was 1890 cyc — the per-step Gpre global load
// (cross-XCD L2 miss -> ~900 cyc) sat naked on the critical path, plus 5
// transcendentals on only 2 waves. Fix: (1) stage all 64x512 Gpre into LDS
// once (128 KB, one-time ~1us) -> zero global loads in the loop; (2) all 512
// threads transform their own gate element (R7 actlds pattern) so the 128-
// thread combine does only 2 fma + 1 tanh.
__global__ __launch_bounds__(512, 1) void k_lstm(const float* __restrict__ Whh,   // 512 x 128
                                                 const float* __restrict__ Gpre,  // 64 x 512
                                                 const float* __restrict__ h0row, // 128
                                                 const float* __restrict__ c0row, // 128
                                                 float* __restrict__ hout)        // 64 x 128
{
    __shared__ __align__(16) float    gpre_lds[64][512];   // 128 KB
    __shared__ __align__(16) _Float16 hh[2][128];
    __shared__ __align__(16) float    g_lds[512];
    __shared__               float    actlds[512];
    const int u    = threadIdx.x;
    const int w    = u >> 6;
    const int l    = u & 63;
    const int lgrp = l >> 4;
    const int lrow = l & 15;

    // stage Gpre -> LDS (contiguous 8192 float4, coalesced)
    for (int it = 0; it < 16; ++it) {
        int idx = it * 512 + u;
        reinterpret_cast<float4*>(&gpre_lds[0][0])[idx] =
            reinterpret_cast<const float4*>(Gpre)[idx];
    }

    // A-frags: Whh slice -> fp16, resident (R12-verified mapping)
    f32x4 araw[4][4];
#pragma unroll
    for (int mt = 0; mt < 4; ++mt) {
#pragma unroll
        for (int kt = 0; kt < 4; ++kt) {
            const float* p = Whh + (size_t)(64 * w + 16 * mt + lrow) * 128 + 32 * kt + 8 * lgrp;
            float4 f0 = *reinterpret_cast<const float4*>(p);
            float4 f1 = *reinterpret_cast<const float4*>(p + 4);
            araw[mt][kt] = __builtin_bit_cast(f32x4, cvt_h8(f0, f1));
        }
    }
#pragma unroll
    for (int mt = 0; mt < 4; ++mt)
#pragma unroll
        for (int kt = 0; kt < 4; ++kt)
            asm volatile("" : "+v"(araw[mt][kt]));   // pin: opaque to remat/sinking

    float c = 0.f;
    if (u < 128) { hh[0][u] = (_Float16)h0row[u]; c = c0row[u]; }
    __syncthreads();

    for (int t = 0; t < 64; ++t) {
        const _Float16* hp = &hh[t & 1][0];
        half8 b0 = *reinterpret_cast<const half8*>(hp + 8 * lgrp);
        half8 b1 = *reinterpret_cast<const half8*>(hp + 32 + 8 * lgrp);
        half8 b2 = *reinterpret_cast<const half8*>(hp + 64 + 8 * lgrp);
        half8 b3 = *reinterpret_cast<const half8*>(hp + 96 + 8 * lgrp);
        f32x4 acc[4];
#pragma unroll
        for (int mt = 0; mt < 4; ++mt) {
            acc[mt] = (f32x4){0.f, 0.f, 0.f, 0.f};
            acc[mt] = __builtin_amdgcn_mfma_f32_16x16x32_f16(
                __builtin_bit_cast(half8, araw[mt][0]), b0, acc[mt], 0, 0, 0);
            acc[mt] = __builtin_amdgcn_mfma_f32_16x16x32_f16(
                __builtin_bit_cast(half8, araw[mt][1]), b1, acc[mt], 0, 0, 0);
            acc[mt] = __builtin_amdgcn_mfma_f32_16x16x32_f16(
                __builtin_bit_cast(half8, araw[mt][2]), b2, acc[mt], 0, 0, 0);
            acc[mt] = __builtin_amdgcn_mfma_f32_16x16x32_f16(
                __builtin_bit_cast(half8, araw[mt][3]), b3, acc[mt], 0, 0, 0);
        }
        if (lrow == 0) {   // D col 0 lanes hold rows 4*lgrp+reg of each tile
#pragma unroll
            for (int mt = 0; mt < 4; ++mt)
                *reinterpret_cast<f32x4*>(&g_lds[64 * w + 16 * mt + 4 * lgrp]) = acc[mt];
        }
        __syncthreads();
        // all 512 threads: activation of own gate element (gate = u>>7)
        {
            float g = g_lds[u] + gpre_lds[t][u];
            actlds[u] = ((u >> 7) == 2) ? tanh_fast(g) : sigmoid_fast(g);
        }
        __syncthreads();
        if (u < 128) {
            float ai = actlds[u], af = actlds[u + 128], ag = actlds[u + 256], ao = actlds[u + 384];
            c = af * c + ai * ag;
            float hn = ao * tanh_fast(c);
            hh[(t + 1) & 1][u] = (_Float16)hn;
            hout[t * 128 + u] = hn;
        }
        __syncthreads();
    }
}

// ---------------- logits via MFMA + split-fp16: 64 x 128001 x 128, NO LDS ----------------
__global__ __launch_bounds__(256, 2) void k_fc(const float* __restrict__ out64,
                                               const float* __restrict__ fcW,
                                               const float* __restrict__ fcb,
                                               float* __restrict__ logits)
{
    const int tid  = threadIdx.x;
    const int w    = tid >> 6;
    const int l    = tid & 63;
    const int lgrp = l >> 4;
    const int lrow = l & 15;

    // A-frags: out64 (64 b x 128 k) -> split fp16, resident (128 VGPR)
    f32x4 ah[4][4], al[4][4];
#pragma unroll
    for (int mt = 0; mt < 4; ++mt) {
#pragma unroll
        for (int kt = 0; kt < 4; ++kt) {
            const float* p = out64 + (size_t)(16 * mt + lrow) * 128 + 32 * kt + 8 * lgrp;
            float4 f0 = *reinterpret_cast<const float4*>(p);
            float4 f1 = *reinterpret_cast<const float4*>(p + 4);
            half8 hi, lo;
            split_h8(f0, f1, hi, lo);
            ah[mt][kt] = __builtin_bit_cast(f32x4, hi);
            al[mt][kt] = __builtin_bit_cast(f32x4, lo);
        }
    }
#pragma unroll
    for (int mt = 0; mt < 4; ++mt)
#pragma unroll
        for (int kt = 0; kt < 4; ++kt) {
            asm volatile("" : "+v"(ah[mt][kt]));
            asm volatile("" : "+v"(al[mt][kt]));
        }

#pragma unroll
    for (int i = 0; i < 2; ++i) {
        int vt = blockIdx.x * 8 + w * 2 + i;        // 16-wide v-tile index
        int v0 = vt * 16;
        if (v0 >= V) break;                          // wave-uniform
        int v  = v0 + lrow;
        int vc = v < V ? v : V - 1;
        // B-frags: fcW row vc, split fp16 (32B/lane, row read once)
        half8 bh[4], bl[4];
#pragma unroll
        for (int kt = 0; kt < 4; ++kt) {
            const float* p = fcW + (size_t)vc * 128 + 32 * kt + 8 * lgrp;
            float4 f0 = *reinterpret_cast<const float4*>(p);
            float4 f1 = *reinterpret_cast<const float4*>(p + 4);
            split_h8(f0, f1, bh[kt], bl[kt]);
        }
        float fb = fcb[vc];
        f32x4 acc[4];
#pragma unroll
        for (int mt = 0; mt < 4; ++mt) {
            acc[mt] = (f32x4){fb, fb, fb, fb};
#pragma unroll
            for (int kt = 0; kt < 4; ++kt) {
                acc[mt] = __builtin_amdgcn_mfma_f32_16x16x32_f16(
                    __builtin_bit_cast(half8, ah[mt][kt]), bh[kt], acc[mt], 0, 0, 0);
                acc[mt] = __builtin_amdgcn_mfma_f32_16x16x32_f16(
                    __builtin_bit_cast(half8, al[mt][kt]), bh[kt], acc[mt], 0, 0, 0);
                acc[mt] = __builtin_amdgcn_mfma_f32_16x16x32_f16(
                    __builtin_bit_cast(half8, ah[mt][kt]), bl[kt], acc[mt], 0, 0, 0);
            }
        }
        if (v < V) {
#pragma unroll
            for (int mt = 0; mt < 4; ++mt)
#pragma unroll
                for (int r = 0; r < 4; ++r)
                    logits[(size_t)(16 * mt + 4 * lgrp + r) * V + v] = acc[mt][r];
        }
    }
}

extern "C" void kernel_launch(void* const* d_in, const int* in_sizes, int n_in,
                              void* d_out, int out_size, void* d_ws, size_t ws_size,
                              hipStream_t stream)
{
    const int*   gnodes = (const int*)d_in[0];
    const int*   src    = (const int*)d_in[1];
    const int*   dst    = (const int*)d_in[2];
    const float* emb    = (const float*)d_in[3];
    const float* gW     = (const float*)d_in[4];
    const float* gb     = (const float*)d_in[5];
    const float* Wih0   = (const float*)d_in[6];
    const float* Whh0   = (const float*)d_in[7];
    const float* bih0   = (const float*)d_in[8];
    const float* bhh0   = (const float*)d_in[9];
    const float* Wih1   = (const float*)d_in[10];
    const float* Whh1   = (const float*)d_in[11];
    const float* bih1   = (const float*)d_in[12];
    const float* bhh1   = (const float*)d_in[13];
    const float* fcW    = (const float*)d_in[14];
    const float* fcb    = (const float*)d_in[15];
    const float* h0     = (const float*)d_in[16];  // (2, 200, 128)
    const float* c0     = (const float*)d_in[17];

    char* ws = (char*)d_ws;
    int*   deg_out = (int*)(ws + 0);          // 12800 ints
    int*   degr    = (int*)(ws + 51200);      // 64 ints
    int*   ecount  = (int*)(ws + 51456);      // 1 int
    float* agg64   = (float*)(ws + 51712);    // 64*128 -> zero region ends at 84480
    int2*  elist   = (int2*)(ws + 84480);     // CAP entries (64 KB) -> 150016
    float* h64     = (float*)(ws + 150016);   // 32 KB -> 182784
    float* Gpre    = (float*)(ws + 182784);   // 128 KB -> 313856 (shared by both layers)
    float* h1out   = (float*)(ws + 313856);   // 32 KB -> 346624
    float* out64   = (float*)(ws + 346624);   // 32 KB -> 379392
    float* logits  = (float*)d_out;

    hipMemsetAsync(ws, 0, 84480, stream);     // deg_out, degr, ecount, agg64

    k_deg_filter<<<E / 256, 256, 0, stream>>>(src, dst, deg_out, degr, ecount, elist);
    k_agg<<<CAP / 2, 256, 0, stream>>>(elist, ecount, gnodes, emb, deg_out, agg64);
    k_h64<<<1, 512, 0, stream>>>(agg64, degr, gW, gb, h64);

    k_gemmG<<<8, 256, 0, stream>>>(h64, Wih0, bih0, bhh0, Gpre);
    k_lstm<<<1, 512, 0, stream>>>(Whh0, Gpre, h0 + 199 * 128, c0 + 199 * 128, h1out);
    k_gemmG<<<8, 256, 0, stream>>>(h1out, Wih1, bih1, bhh1, Gpre);
    k_lstm<<<1, 512, 0, stream>>>(Whh1, Gpre, h0 + (200 + 199) * 128, c0 + (200 + 199) * 128, out64);

    // ceil(ceil(V/16)/8) = 1001 blocks: covers all 8001 v-tiles incl. v=128000
    k_fc<<<1001, 256, 0, stream>>>(out64, fcW, fcb, logits);
}

// Round 17
// 194.026 us; speedup vs baseline: 1.1321x; 1.1321x over previous
//
#include <hip/hip_runtime.h>
#include <cstdint>
#include <cstddef>

constexpr int V   = 128001;
constexpr int D   = 128;
constexpr int S   = 200;
constexpr int E   = 409600;
constexpr int G4  = 512;
constexpr int CAP = 8192;

typedef _Float16 half8 __attribute__((ext_vector_type(8)));
typedef float    f32x4 __attribute__((ext_vector_type(4)));

__device__ __forceinline__ float rcp_fast(float x) {
    float r;
    asm volatile("v_rcp_f32 %0, %1" : "=v"(r) : "v"(x));
    return r;
}
__device__ __forceinline__ float sigmoid_fast(float x) {
    x = fminf(fmaxf(x, -15.f), 15.f);
    return rcp_fast(1.f + __expf(-x));
}
__device__ __forceinline__ float tanh_fast(float x) {
    x = fminf(fmaxf(x, -7.5f), 7.5f);
    float e = __expf(2.f * x);
    return (e - 1.f) * rcp_fast(e + 1.f);
}
__device__ __forceinline__ half8 cvt_h8(float4 f0, float4 f1) {
    half8 h = {(_Float16)f0.x, (_Float16)f0.y, (_Float16)f0.z, (_Float16)f0.w,
               (_Float16)f1.x, (_Float16)f1.y, (_Float16)f1.z, (_Float16)f1.w};
    return h;
}
// split-fp16: hi = fp16(x), lo = fp16(x - hi); hi+lo carries ~22 mantissa bits
__device__ __forceinline__ void split_h8(float4 f0, float4 f1, half8& hi, half8& lo) {
    hi = cvt_h8(f0, f1);
    half8 l = {(_Float16)(f0.x - (float)hi[0]), (_Float16)(f0.y - (float)hi[1]),
               (_Float16)(f0.z - (float)hi[2]), (_Float16)(f0.w - (float)hi[3]),
               (_Float16)(f1.x - (float)hi[4]), (_Float16)(f1.y - (float)hi[5]),
               (_Float16)(f1.z - (float)hi[6]), (_Float16)(f1.w - (float)hi[7])};
    lo = l;
}
// runtime element select from f32x4 (3 cndmask, stays in registers)
__device__ __forceinline__ float sel4(f32x4 v, int r) {
    float x01 = (r & 1) ? v[1] : v[0];
    float x23 = (r & 1) ? v[3] : v[2];
    return (r & 2) ? x23 : x01;
}

// ---------------- degree pass + edge filter (dst % 200 == 199) ----------------
__global__ void k_deg_filter(const int* __restrict__ src, const int* __restrict__ dst,
                             int* __restrict__ deg_out, int* __restrict__ degr,
                             int* __restrict__ ecount, int2* __restrict__ elist)
{
    int e = blockIdx.x * blockDim.x + threadIdx.x;
    if (e >= E) return;
    int s = src[e], d = dst[e];
    atomicAdd(&deg_out[s], 1);
    if (d % S == S - 1) {
        int b = d / S;
        atomicAdd(&degr[b], 1);
        int p = atomicAdd(ecount, 1);
        if (p < CAP) elist[p] = make_int2(s, b);
    }
}

// ---------------- aggregate filtered edges ----------------
__global__ void k_agg(const int2* __restrict__ elist, const int* __restrict__ ecount,
                      const int* __restrict__ gnodes, const float* __restrict__ emb,
                      const int* __restrict__ deg_out, float* __restrict__ agg64)
{
    int cnt = *ecount; if (cnt > CAP) cnt = CAP;
    int idx = blockIdx.x * 2 + (threadIdx.x >> 7);
    int d   = threadIdx.x & 127;
    if (idx >= cnt) return;
    int2 eb = elist[idx];
    int s = eb.x, b = eb.y;
    int dg = deg_out[s];
    float ns = (dg > 0) ? rsqrtf((float)dg) : 0.f;
    float v = emb[(size_t)gnodes[s] * D + d] * ns;
    atomicAdd(&agg64[b * D + d], v);
}

// ---------------- h64 = relu((agg64 * n_dst) @ gW + gb), 64x128 ----------------
__global__ __launch_bounds__(512) void k_h64(const float* __restrict__ agg64,
                                             const int* __restrict__ degr,
                                             const float* __restrict__ gW,
                                             const float* __restrict__ gb,
                                             float* __restrict__ h64)
{
    __shared__ float a[64][128];
    for (int i = threadIdx.x; i < 64 * 128; i += blockDim.x) {
        int b = i >> 7;
        int dg = degr[b];
        float nd = (dg > 0) ? rsqrtf((float)dg) : 0.f;
        a[b][i & 127] = agg64[i] * nd;
    }
    __syncthreads();
    int j  = threadIdx.x & 127;
    int bg = threadIdx.x >> 7;
    float acc[16];
    float bias = gb[j];
#pragma unroll
    for (int ii = 0; ii < 16; ++ii) acc[ii] = bias;
    for (int k = 0; k < 128; ++k) {
        float w = gW[k * 128 + j];
#pragma unroll
        for (int ii = 0; ii < 16; ++ii) acc[ii] = fmaf(a[bg * 16 + ii][k], w, acc[ii]);
    }
#pragma unroll
    for (int ii = 0; ii < 16; ++ii)
        h64[(bg * 16 + ii) * 128 + j] = fmaxf(acc[ii], 0.f);
}

// ---------------- Gpre[t][u] = A[t] . Wih[u] + b1[u] + b2[u]  (64 x 512) ----------------
__global__ __launch_bounds__(256) void k_gemmG(const float* __restrict__ A,
                                               const float* __restrict__ Wih,
                                               const float* __restrict__ b1,
                                               const float* __restrict__ b2,
                                               float* __restrict__ Gpre)
{
    __shared__ float a[16][128];
    int tq = blockIdx.x >> 1;
    int ub = blockIdx.x & 1;
    for (int i = threadIdx.x; i < 16 * 128; i += 256)
        a[i >> 7][i & 127] = A[(tq * 16 + (i >> 7)) * 128 + (i & 127)];
    __syncthreads();
    int u = ub * 256 + threadIdx.x;
    float bias = b1[u] + b2[u];
    float acc[16];
#pragma unroll
    for (int t = 0; t < 16; ++t) acc[t] = bias;
    const float4* wr = reinterpret_cast<const float4*>(Wih + (size_t)u * 128);
    for (int k4 = 0; k4 < 32; ++k4) {
        float4 w4 = wr[k4];
#pragma unroll
        for (int t = 0; t < 16; ++t) {
            float4 av = *reinterpret_cast<const float4*>(&a[t][k4 * 4]);
            acc[t] += fmaf(w4.x, av.x, fmaf(w4.y, av.y, fmaf(w4.z, av.z, w4.w * av.w)));
        }
    }
#pragma unroll
    for (int t = 0; t < 16; ++t) Gpre[(tq * 16 + t) * G4 + u] = acc[t];
}

// ---------------- single-row LSTM via MFMA, gate-partitioned tiles ----------------
// R16 post-mortem: step = ~1890 cyc, invariant to Gpre location / act spread —
// the cost is 3 barriers + 3 LDS round trips per step. Since B (=h) is
// replicated across MFMA columns, every lane holds its tile's full 4-row
// result in acc[mt]. Gate-partitioned tiling (tile mt = gate mt, rows
// 16w..16w+15) puts i,f,g,o for one h-row in ONE lane's registers -> the
// whole combine is in-register: select acc[mt][lrow], + gpre (LDS), act,
// private c, write h. ONE barrier per step, zero g_lds/actlds hops.
__global__ __launch_bounds__(512, 1) void k_lstm(const float* __restrict__ Whh,   // 512 x 128
                                                 const float* __restrict__ Gpre,  // 64 x 512
                                                 const float* __restrict__ h0row, // 128
                                                 const float* __restrict__ c0row, // 128
                                                 float* __restrict__ hout)        // 64 x 128
{
    __shared__ __align__(16) float    gpre_lds[64][512];   // 128 KB
    __shared__ __align__(16) _Float16 hh[2][128];
    const int u    = threadIdx.x;
    const int w    = u >> 6;           // wave: owns h-rows 16w..16w+15 (all 4 gates)
    const int l    = u & 63;
    const int lgrp = l >> 4;
    const int lrow = l & 15;

    // stage Gpre -> LDS (contiguous 8192 float4, coalesced)
    for (int it = 0; it < 16; ++it) {
        int idx = it * 512 + u;
        reinterpret_cast<float4*>(&gpre_lds[0][0])[idx] =
            reinterpret_cast<const float4*>(Gpre)[idx];
    }

    // A-frags, gate-partitioned: tile mt = gate mt, global row mt*128 + 16w + lrow
    f32x4 araw[4][4];
#pragma unroll
    for (int mt = 0; mt < 4; ++mt) {
#pragma unroll
        for (int kt = 0; kt < 4; ++kt) {
            const float* p = Whh + (size_t)(mt * 128 + 16 * w + lrow) * 128 + 32 * kt + 8 * lgrp;
            float4 f0 = *reinterpret_cast<const float4*>(p);
            float4 f1 = *reinterpret_cast<const float4*>(p + 4);
            araw[mt][kt] = __builtin_bit_cast(f32x4, cvt_h8(f0, f1));
        }
    }
#pragma unroll
    for (int mt = 0; mt < 4; ++mt)
#pragma unroll
        for (int kt = 0; kt < 4; ++kt)
            asm volatile("" : "+v"(araw[mt][kt]));   // pin: opaque to remat/sinking

    const bool comb  = (lrow < 4);
    const int  myrow = 16 * w + 4 * lgrp + lrow;     // h-row this lane combines
    float c = 0.f;
    if (u < 128) hh[0][u] = (_Float16)h0row[u];
    if (comb)    c = c0row[myrow];
    __syncthreads();

    for (int t = 0; t < 64; ++t) {
        const _Float16* hp = &hh[t & 1][0];
        half8 b0 = *reinterpret_cast<const half8*>(hp + 8 * lgrp);
        half8 b1 = *reinterpret_cast<const half8*>(hp + 32 + 8 * lgrp);
        half8 b2 = *reinterpret_cast<const half8*>(hp + 64 + 8 * lgrp);
        half8 b3 = *reinterpret_cast<const half8*>(hp + 96 + 8 * lgrp);
        f32x4 acc[4];
#pragma unroll
        for (int mt = 0; mt < 4; ++mt) {
            acc[mt] = (f32x4){0.f, 0.f, 0.f, 0.f};
            acc[mt] = __builtin_amdgcn_mfma_f32_16x16x32_f16(
                __builtin_bit_cast(half8, araw[mt][0]), b0, acc[mt], 0, 0, 0);
            acc[mt] = __builtin_amdgcn_mfma_f32_16x16x32_f16(
                __builtin_bit_cast(half8, araw[mt][1]), b1, acc[mt], 0, 0, 0);
            acc[mt] = __builtin_amdgcn_mfma_f32_16x16x32_f16(
                __builtin_bit_cast(half8, araw[mt][2]), b2, acc[mt], 0, 0, 0);
            acc[mt] = __builtin_amdgcn_mfma_f32_16x16x32_f16(
                __builtin_bit_cast(half8, araw[mt][3]), b3, acc[mt], 0, 0, 0);
        }
        if (comb) {
            // in-register gate combine for h-row `myrow`
            float gi = sel4(acc[0], lrow) + gpre_lds[t][myrow];
            float gf = sel4(acc[1], lrow) + gpre_lds[t][128 + myrow];
            float gg = sel4(acc[2], lrow) + gpre_lds[t][256 + myrow];
            float go = sel4(acc[3], lrow) + gpre_lds[t][384 + myrow];
            float si = sigmoid_fast(gi);
            float sf = sigmoid_fast(gf);
            float so = sigmoid_fast(go);
            c = sf * c + si * tanh_fast(gg);
            float hn = so * tanh_fast(c);
            hh[(t + 1) & 1][myrow] = (_Float16)hn;
            hout[t * 128 + myrow] = hn;
        }
        __syncthreads();
    }
}

// ---------------- logits via MFMA + split-fp16: 64 x 128001 x 128, NO LDS ----------------
__global__ __launch_bounds__(256, 2) void k_fc(const float* __restrict__ out64,
                                               const float* __restrict__ fcW,
                                               const float* __restrict__ fcb,
                                               float* __restrict__ logits)
{
    const int tid  = threadIdx.x;
    const int w    = tid >> 6;
    const int l    = tid & 63;
    const int lgrp = l >> 4;
    const int lrow = l & 15;

    // A-frags: out64 (64 b x 128 k) -> split fp16, resident (128 VGPR)
    f32x4 ah[4][4], al[4][4];
#pragma unroll
    for (int mt = 0; mt < 4; ++mt) {
#pragma unroll
        for (int kt = 0; kt < 4; ++kt) {
            const float* p = out64 + (size_t)(16 * mt + lrow) * 128 + 32 * kt + 8 * lgrp;
            float4 f0 = *reinterpret_cast<const float4*>(p);
            float4 f1 = *reinterpret_cast<const float4*>(p + 4);
            half8 hi, lo;
            split_h8(f0, f1, hi, lo);
            ah[mt][kt] = __builtin_bit_cast(f32x4, hi);
            al[mt][kt] = __builtin_bit_cast(f32x4, lo);
        }
    }
#pragma unroll
    for (int mt = 0; mt < 4; ++mt)
#pragma unroll
        for (int kt = 0; kt < 4; ++kt) {
            asm volatile("" : "+v"(ah[mt][kt]));
            asm volatile("" : "+v"(al[mt][kt]));
        }

#pragma unroll
    for (int i = 0; i < 2; ++i) {
        int vt = blockIdx.x * 8 + w * 2 + i;        // 16-wide v-tile index
        int v0 = vt * 16;
        if (v0 >= V) break;                          // wave-uniform
        int v  = v0 + lrow;
        int vc = v < V ? v : V - 1;
        // B-frags: fcW row vc, split fp16 (32B/lane, row read once)
        half8 bh[4], bl[4];
#pragma unroll
        for (int kt = 0; kt < 4; ++kt) {
            const float* p = fcW + (size_t)vc * 128 + 32 * kt + 8 * lgrp;
            float4 f0 = *reinterpret_cast<const float4*>(p);
            float4 f1 = *reinterpret_cast<const float4*>(p + 4);
            split_h8(f0, f1, bh[kt], bl[kt]);
        }
        float fb = fcb[vc];
        f32x4 acc[4];
#pragma unroll
        for (int mt = 0; mt < 4; ++mt) {
            acc[mt] = (f32x4){fb, fb, fb, fb};
#pragma unroll
            for (int kt = 0; kt < 4; ++kt) {
                acc[mt] = __builtin_amdgcn_mfma_f32_16x16x32_f16(
                    __builtin_bit_cast(half8, ah[mt][kt]), bh[kt], acc[mt], 0, 0, 0);
                acc[mt] = __builtin_amdgcn_mfma_f32_16x16x32_f16(
                    __builtin_bit_cast(half8, al[mt][kt]), bh[kt], acc[mt], 0, 0, 0);
                acc[mt] = __builtin_amdgcn_mfma_f32_16x16x32_f16(
                    __builtin_bit_cast(half8, ah[mt][kt]), bl[kt], acc[mt], 0, 0, 0);
            }
        }
        if (v < V) {
#pragma unroll
            for (int mt = 0; mt < 4; ++mt)
#pragma unroll
                for (int r = 0; r < 4; ++r)
                    logits[(size_t)(16 * mt + 4 * lgrp + r) * V + v] = acc[mt][r];
        }
    }
}

extern "C" void kernel_launch(void* const* d_in, const int* in_sizes, int n_in,
                              void* d_out, int out_size, void* d_ws, size_t ws_size,
                              hipStream_t stream)
{
    const int*   gnodes = (const int*)d_in[0];
    const int*   src    = (const int*)d_in[1];
    const int*   dst    = (const int*)d_in[2];
    const float* emb    = (const float*)d_in[3];
    const float* gW     = (const float*)d_in[4];
    const float* gb     = (const float*)d_in[5];
    const float* Wih0   = (const float*)d_in[6];
    const float* Whh0   = (const float*)d_in[7];
    const float* bih0   = (const float*)d_in[8];
    const float* bhh0   = (const float*)d_in[9];
    const float* Wih1   = (const float*)d_in[10];
    const float* Whh1   = (const float*)d_in[11];
    const float* bih1   = (const float*)d_in[12];
    const float* bhh1   = (const float*)d_in[13];
    const float* fcW    = (const float*)d_in[14];
    const float* fcb    = (const float*)d_in[15];
    const float* h0     = (const float*)d_in[16];  // (2, 200, 128)
    const float* c0     = (const float*)d_in[17];

    char* ws = (char*)d_ws;
    int*   deg_out = (int*)(ws + 0);          // 12800 ints
    int*   degr    = (int*)(ws + 51200);      // 64 ints
    int*   ecount  = (int*)(ws + 51456);      // 1 int
    float* agg64   = (float*)(ws + 51712);    // 64*128 -> zero region ends at 84480
    int2*  elist   = (int2*)(ws + 84480);     // CAP entries (64 KB) -> 150016
    float* h64     = (float*)(ws + 150016);   // 32 KB -> 182784
    float* Gpre    = (float*)(ws + 182784);   // 128 KB -> 313856 (shared by both layers)
    float* h1out   = (float*)(ws + 313856);   // 32 KB -> 346624
    float* out64   = (float*)(ws + 346624);   // 32 KB -> 379392
    float* logits  = (float*)d_out;

    hipMemsetAsync(ws, 0, 84480, stream);     // deg_out, degr, ecount, agg64

    k_deg_filter<<<E / 256, 256, 0, stream>>>(src, dst, deg_out, degr, ecount, elist);
    k_agg<<<CAP / 2, 256, 0, stream>>>(elist, ecount, gnodes, emb, deg_out, agg64);
    k_h64<<<1, 512, 0, stream>>>(agg64, degr, gW, gb, h64);

    k_gemmG<<<8, 256, 0, stream>>>(h64, Wih0, bih0, bhh0, Gpre);
    k_lstm<<<1, 512, 0, stream>>>(Whh0, Gpre, h0 + 199 * 128, c0 + 199 * 128, h1out);
    k_gemmG<<<8, 256, 0, stream>>>(h1out, Wih1, bih1, bhh1, Gpre);
    k_lstm<<<1, 512, 0, stream>>>(Whh1, Gpre, h0 + (200 + 199) * 128, c0 + (200 + 199) * 128, out64);

    // ceil(ceil(V/16)/8) = 1001 blocks: covers all 8001 v-tiles incl. v=128000
    k_fc<<<1001, 256, 0, stream>>>(out64, fcW, fcb, logits);
}

// Round 18
// 184.705 us; speedup vs baseline: 1.1892x; 1.0505x over previous
//
#include <hip/hip_runtime.h>
#include <cstdint>
#include <cstddef>

constexpr int V   = 128001;
constexpr int D   = 128;
constexpr int S   = 200;
constexpr int E   = 409600;
constexpr int G4  = 512;
constexpr int CAP = 8192;

typedef _Float16 half8 __attribute__((ext_vector_type(8)));
typedef float    f32x4 __attribute__((ext_vector_type(4)));

__device__ __forceinline__ float rcp_fast(float x) {
    float r;
    asm volatile("v_rcp_f32 %0, %1" : "=v"(r) : "v"(x));
    return r;
}
__device__ __forceinline__ float sigmoid_fast(float x) {
    x = fminf(fmaxf(x, -15.f), 15.f);
    return rcp_fast(1.f + __expf(-x));
}
__device__ __forceinline__ float tanh_fast(float x) {
    x = fminf(fmaxf(x, -7.5f), 7.5f);
    float e = __expf(2.f * x);
    return (e - 1.f) * rcp_fast(e + 1.f);
}
__device__ __forceinline__ half8 cvt_h8(float4 f0, float4 f1) {
    half8 h = {(_Float16)f0.x, (_Float16)f0.y, (_Float16)f0.z, (_Float16)f0.w,
               (_Float16)f1.x, (_Float16)f1.y, (_Float16)f1.z, (_Float16)f1.w};
    return h;
}
// split-fp16: hi = fp16(x), lo = fp16(x - hi); hi+lo carries ~22 mantissa bits
__device__ __forceinline__ void split_h8(float4 f0, float4 f1, half8& hi, half8& lo) {
    hi = cvt_h8(f0, f1);
    half8 l = {(_Float16)(f0.x - (float)hi[0]), (_Float16)(f0.y - (float)hi[1]),
               (_Float16)(f0.z - (float)hi[2]), (_Float16)(f0.w - (float)hi[3]),
               (_Float16)(f1.x - (float)hi[4]), (_Float16)(f1.y - (float)hi[5]),
               (_Float16)(f1.z - (float)hi[6]), (_Float16)(f1.w - (float)hi[7])};
    lo = l;
}
// runtime element select from f32x4 (3 cndmask, stays in registers)
__device__ __forceinline__ float sel4(f32x4 v, int r) {
    float x01 = (r & 1) ? v[1] : v[0];
    float x23 = (r & 1) ? v[3] : v[2];
    return (r & 2) ? x23 : x01;
}

// ---------------- degree pass + edge filter (dst % 200 == 199) ----------------
__global__ void k_deg_filter(const int* __restrict__ src, const int* __restrict__ dst,
                             int* __restrict__ deg_out, int* __restrict__ degr,
                             int* __restrict__ ecount, int2* __restrict__ elist)
{
    int e = blockIdx.x * blockDim.x + threadIdx.x;
    if (e >= E) return;
    int s = src[e], d = dst[e];
    atomicAdd(&deg_out[s], 1);
    if (d % S == S - 1) {
        int b = d / S;
        atomicAdd(&degr[b], 1);
        int p = atomicAdd(ecount, 1);
        if (p < CAP) elist[p] = make_int2(s, b);
    }
}

// ---------------- aggregate filtered edges ----------------
__global__ void k_agg(const int2* __restrict__ elist, const int* __restrict__ ecount,
                      const int* __restrict__ gnodes, const float* __restrict__ emb,
                      const int* __restrict__ deg_out, float* __restrict__ agg64)
{
    int cnt = *ecount; if (cnt > CAP) cnt = CAP;
    int idx = blockIdx.x * 2 + (threadIdx.x >> 7);
    int d   = threadIdx.x & 127;
    if (idx >= cnt) return;
    int2 eb = elist[idx];
    int s = eb.x, b = eb.y;
    int dg = deg_out[s];
    float ns = (dg > 0) ? rsqrtf((float)dg) : 0.f;
    float v = emb[(size_t)gnodes[s] * D + d] * ns;
    atomicAdd(&agg64[b * D + d], v);
}

// ---------------- h64 = relu((agg64 * n_dst) @ gW + gb), 64x128 ----------------
__global__ __launch_bounds__(512) void k_h64(const float* __restrict__ agg64,
                                             const int* __restrict__ degr,
                                             const float* __restrict__ gW,
                                             const float* __restrict__ gb,
                                             float* __restrict__ h64)
{
    __shared__ float a[64][128];
    for (int i = threadIdx.x; i < 64 * 128; i += blockDim.x) {
        int b = i >> 7;
        int dg = degr[b];
        float nd = (dg > 0) ? rsqrtf((float)dg) : 0.f;
        a[b][i & 127] = agg64[i] * nd;
    }
    __syncthreads();
    int j  = threadIdx.x & 127;
    int bg = threadIdx.x >> 7;
    float acc[16];
    float bias = gb[j];
#pragma unroll
    for (int ii = 0; ii < 16; ++ii) acc[ii] = bias;
    for (int k = 0; k < 128; ++k) {
        float w = gW[k * 128 + j];
#pragma unroll
        for (int ii = 0; ii < 16; ++ii) acc[ii] = fmaf(a[bg * 16 + ii][k], w, acc[ii]);
    }
#pragma unroll
    for (int ii = 0; ii < 16; ++ii)
        h64[(bg * 16 + ii) * 128 + j] = fmaxf(acc[ii], 0.f);
}

// ---------------- Gpre[t][u] = A[t] . Wih[u] + b1[u] + b2[u]  (64 x 512) ----------------
__global__ __launch_bounds__(256) void k_gemmG(const float* __restrict__ A,
                                               const float* __restrict__ Wih,
                                               const float* __restrict__ b1,
                                               const float* __restrict__ b2,
                                               float* __restrict__ Gpre)
{
    __shared__ float a[16][128];
    int tq = blockIdx.x >> 1;
    int ub = blockIdx.x & 1;
    for (int i = threadIdx.x; i < 16 * 128; i += 256)
        a[i >> 7][i & 127] = A[(tq * 16 + (i >> 7)) * 128 + (i & 127)];
    __syncthreads();
    int u = ub * 256 + threadIdx.x;
    float bias = b1[u] + b2[u];
    float acc[16];
#pragma unroll
    for (int t = 0; t < 16; ++t) acc[t] = bias;
    const float4* wr = reinterpret_cast<const float4*>(Wih + (size_t)u * 128);
    for (int k4 = 0; k4 < 32; ++k4) {
        float4 w4 = wr[k4];
#pragma unroll
        for (int t = 0; t < 16; ++t) {
            float4 av = *reinterpret_cast<const float4*>(&a[t][k4 * 4]);
            acc[t] += fmaf(w4.x, av.x, fmaf(w4.y, av.y, fmaf(w4.z, av.z, w4.w * av.w)));
        }
    }
#pragma unroll
    for (int t = 0; t < 16; ++t) Gpre[(tq * 16 + t) * G4 + u] = acc[t];
}

// ---------------- single-row LSTM via MFMA, gate-partitioned tiles (R17, works) ----------------
__global__ __launch_bounds__(512, 1) void k_lstm(const float* __restrict__ Whh,   // 512 x 128
                                                 const float* __restrict__ Gpre,  // 64 x 512
                                                 const float* __restrict__ h0row, // 128
                                                 const float* __restrict__ c0row, // 128
                                                 float* __restrict__ hout)        // 64 x 128
{
    __shared__ __align__(16) float    gpre_lds[64][512];   // 128 KB
    __shared__ __align__(16) _Float16 hh[2][128];
    const int u    = threadIdx.x;
    const int w    = u >> 6;           // wave: owns h-rows 16w..16w+15 (all 4 gates)
    const int l    = u & 63;
    const int lgrp = l >> 4;
    const int lrow = l & 15;

    for (int it = 0; it < 16; ++it) {
        int idx = it * 512 + u;
        reinterpret_cast<float4*>(&gpre_lds[0][0])[idx] =
            reinterpret_cast<const float4*>(Gpre)[idx];
    }

    // A-frags, gate-partitioned: tile mt = gate mt, global row mt*128 + 16w + lrow
    f32x4 araw[4][4];
#pragma unroll
    for (int mt = 0; mt < 4; ++mt) {
#pragma unroll
        for (int kt = 0; kt < 4; ++kt) {
            const float* p = Whh + (size_t)(mt * 128 + 16 * w + lrow) * 128 + 32 * kt + 8 * lgrp;
            float4 f0 = *reinterpret_cast<const float4*>(p);
            float4 f1 = *reinterpret_cast<const float4*>(p + 4);
            araw[mt][kt] = __builtin_bit_cast(f32x4, cvt_h8(f0, f1));
        }
    }
#pragma unroll
    for (int mt = 0; mt < 4; ++mt)
#pragma unroll
        for (int kt = 0; kt < 4; ++kt)
            asm volatile("" : "+v"(araw[mt][kt]));   // pin: opaque to remat/sinking

    const bool comb  = (lrow < 4);
    const int  myrow = 16 * w + 4 * lgrp + lrow;     // h-row this lane combines
    float c = 0.f;
    if (u < 128) hh[0][u] = (_Float16)h0row[u];
    if (comb)    c = c0row[myrow];
    __syncthreads();

    for (int t = 0; t < 64; ++t) {
        const _Float16* hp = &hh[t & 1][0];
        half8 b0 = *reinterpret_cast<const half8*>(hp + 8 * lgrp);
        half8 b1 = *reinterpret_cast<const half8*>(hp + 32 + 8 * lgrp);
        half8 b2 = *reinterpret_cast<const half8*>(hp + 64 + 8 * lgrp);
        half8 b3 = *reinterpret_cast<const half8*>(hp + 96 + 8 * lgrp);
        f32x4 acc[4];
#pragma unroll
        for (int mt = 0; mt < 4; ++mt) {
            acc[mt] = (f32x4){0.f, 0.f, 0.f, 0.f};
            acc[mt] = __builtin_amdgcn_mfma_f32_16x16x32_f16(
                __builtin_bit_cast(half8, araw[mt][0]), b0, acc[mt], 0, 0, 0);
            acc[mt] = __builtin_amdgcn_mfma_f32_16x16x32_f16(
                __builtin_bit_cast(half8, araw[mt][1]), b1, acc[mt], 0, 0, 0);
            acc[mt] = __builtin_amdgcn_mfma_f32_16x16x32_f16(
                __builtin_bit_cast(half8, araw[mt][2]), b2, acc[mt], 0, 0, 0);
            acc[mt] = __builtin_amdgcn_mfma_f32_16x16x32_f16(
                __builtin_bit_cast(half8, araw[mt][3]), b3, acc[mt], 0, 0, 0);
        }
        if (comb) {
            float gi = sel4(acc[0], lrow) + gpre_lds[t][myrow];
            float gf = sel4(acc[1], lrow) + gpre_lds[t][128 + myrow];
            float gg = sel4(acc[2], lrow) + gpre_lds[t][256 + myrow];
            float go = sel4(acc[3], lrow) + gpre_lds[t][384 + myrow];
            float si = sigmoid_fast(gi);
            float sf = sigmoid_fast(gf);
            float so = sigmoid_fast(go);
            c = sf * c + si * tanh_fast(gg);
            float hn = so * tanh_fast(c);
            hh[(t + 1) & 1][myrow] = (_Float16)hn;
            hout[t * 128 + myrow] = hn;
        }
        __syncthreads();
    }
}

// ---------------- pre-split out64 into k_fc's A-fragment order ----------------
// slot = ((mt*4+kt)*4+lgrp)*16 + lrow  ->  rows 16mt+lrow, k = 32kt+8lgrp..+8
// Removes the per-block redundant fp32->split-fp16 conversion (was ~500 VALU
// cyc x 1001 blocks) and guarantees A-frag loads are pure 16B half8 loads.
__global__ __launch_bounds__(512) void k_splitA(const float* __restrict__ out64,
                                                _Float16* __restrict__ AH,
                                                _Float16* __restrict__ AL)
{
    for (int i = 0; i < 2; ++i) {
        int slot = i * 512 + threadIdx.x;
        int lrow = slot & 15;
        int lgrp = (slot >> 4) & 3;
        int kt   = (slot >> 6) & 3;
        int mt   = slot >> 8;
        const float* p = out64 + (size_t)(16 * mt + lrow) * 128 + 32 * kt + 8 * lgrp;
        float4 f0 = *reinterpret_cast<const float4*>(p);
        float4 f1 = *reinterpret_cast<const float4*>(p + 4);
        half8 hi, lo;
        split_h8(f0, f1, hi, lo);
        *reinterpret_cast<half8*>(AH + (size_t)slot * 8) = hi;
        *reinterpret_cast<half8*>(AL + (size_t)slot * 8) = lo;
    }
}

// ---------------- logits via MFMA + split-fp16: 64 x 128001 x 128, NO LDS ----------------
// R17 post-mortem: latency-bound (MfmaUtil 4.5%, VALUBusy 9%, Occ 16%).
// Fixes: (1) A-frags pre-split by k_splitA -> 32 pure 16B loads, no cvt VALU;
// (2) both v-tiles' raw B loaded upfront (8 x 32B in flight) -> fcW latency
// exposed once per wave, not twice; no `break` (predicated stores).
__global__ __launch_bounds__(256, 2) void k_fc(const _Float16* __restrict__ AH,
                                               const _Float16* __restrict__ AL,
                                               const float* __restrict__ fcW,
                                               const float* __restrict__ fcb,
                                               float* __restrict__ logits)
{
    const int tid  = threadIdx.x;
    const int w    = tid >> 6;
    const int l    = tid & 63;
    const int lgrp = l >> 4;
    const int lrow = l & 15;

    // A-frags: pure half8 loads in fragment order (identical across waves -> L1)
    f32x4 ah[4][4], al[4][4];
#pragma unroll
    for (int mt = 0; mt < 4; ++mt) {
#pragma unroll
        for (int kt = 0; kt < 4; ++kt) {
            int slot = ((mt * 4 + kt) * 4 + lgrp) * 16 + lrow;
            ah[mt][kt] = __builtin_bit_cast(f32x4,
                *reinterpret_cast<const half8*>(AH + (size_t)slot * 8));
            al[mt][kt] = __builtin_bit_cast(f32x4,
                *reinterpret_cast<const half8*>(AL + (size_t)slot * 8));
        }
    }
#pragma unroll
    for (int mt = 0; mt < 4; ++mt)
#pragma unroll
        for (int kt = 0; kt < 4; ++kt) {
            asm volatile("" : "+v"(ah[mt][kt]));
            asm volatile("" : "+v"(al[mt][kt]));
        }

    const int vt0 = blockIdx.x * 8 + w * 2;
    const int vt1 = vt0 + 1;
    const int v0  = vt0 * 16 + lrow;
    const int v1  = vt1 * 16 + lrow;
    const int vc0 = v0 < V ? v0 : V - 1;
    const int vc1 = v1 < V ? v1 : V - 1;
    const bool p0 = v0 < V;
    const bool p1 = v1 < V;

    // raw B for BOTH tiles upfront: 8 x 32B loads in flight
    float4 r0[4][2], r1[4][2];
#pragma unroll
    for (int kt = 0; kt < 4; ++kt) {
        const float* p = fcW + (size_t)vc0 * 128 + 32 * kt + 8 * lgrp;
        r0[kt][0] = *reinterpret_cast<const float4*>(p);
        r0[kt][1] = *reinterpret_cast<const float4*>(p + 4);
    }
#pragma unroll
    for (int kt = 0; kt < 4; ++kt) {
        const float* p = fcW + (size_t)vc1 * 128 + 32 * kt + 8 * lgrp;
        r1[kt][0] = *reinterpret_cast<const float4*>(p);
        r1[kt][1] = *reinterpret_cast<const float4*>(p + 4);
    }
    const float fb0 = fcb[vc0];
    const float fb1 = fcb[vc1];

    // tile 0
    {
        half8 bh[4], bl[4];
#pragma unroll
        for (int kt = 0; kt < 4; ++kt) split_h8(r0[kt][0], r0[kt][1], bh[kt], bl[kt]);
        f32x4 acc[4];
#pragma unroll
        for (int mt = 0; mt < 4; ++mt) {
            acc[mt] = (f32x4){fb0, fb0, fb0, fb0};
#pragma unroll
            for (int kt = 0; kt < 4; ++kt) {
                acc[mt] = __builtin_amdgcn_mfma_f32_16x16x32_f16(
                    __builtin_bit_cast(half8, ah[mt][kt]), bh[kt], acc[mt], 0, 0, 0);
                acc[mt] = __builtin_amdgcn_mfma_f32_16x16x32_f16(
                    __builtin_bit_cast(half8, al[mt][kt]), bh[kt], acc[mt], 0, 0, 0);
                acc[mt] = __builtin_amdgcn_mfma_f32_16x16x32_f16(
                    __builtin_bit_cast(half8, ah[mt][kt]), bl[kt], acc[mt], 0, 0, 0);
            }
        }
        if (p0) {
#pragma unroll
            for (int mt = 0; mt < 4; ++mt)
#pragma unroll
                for (int r = 0; r < 4; ++r)
                    logits[(size_t)(16 * mt + 4 * lgrp + r) * V + v0] = acc[mt][r];
        }
    }
    // tile 1
    {
        half8 bh[4], bl[4];
#pragma unroll
        for (int kt = 0; kt < 4; ++kt) split_h8(r1[kt][0], r1[kt][1], bh[kt], bl[kt]);
        f32x4 acc[4];
#pragma unroll
        for (int mt = 0; mt < 4; ++mt) {
            acc[mt] = (f32x4){fb1, fb1, fb1, fb1};
#pragma unroll
            for (int kt = 0; kt < 4; ++kt) {
                acc[mt] = __builtin_amdgcn_mfma_f32_16x16x32_f16(
                    __builtin_bit_cast(half8, ah[mt][kt]), bh[kt], acc[mt], 0, 0, 0);
                acc[mt] = __builtin_amdgcn_mfma_f32_16x16x32_f16(
                    __builtin_bit_cast(half8, al[mt][kt]), bh[kt], acc[mt], 0, 0, 0);
                acc[mt] = __builtin_amdgcn_mfma_f32_16x16x32_f16(
                    __builtin_bit_cast(half8, ah[mt][kt]), bl[kt], acc[mt], 0, 0, 0);
            }
        }
        if (p1) {
#pragma unroll
            for (int mt = 0; mt < 4; ++mt)
#pragma unroll
                for (int r = 0; r < 4; ++r)
                    logits[(size_t)(16 * mt + 4 * lgrp + r) * V + v1] = acc[mt][r];
        }
    }
}

extern "C" void kernel_launch(void* const* d_in, const int* in_sizes, int n_in,
                              void* d_out, int out_size, void* d_ws, size_t ws_size,
                              hipStream_t stream)
{
    const int*   gnodes = (const int*)d_in[0];
    const int*   src    = (const int*)d_in[1];
    const int*   dst    = (const int*)d_in[2];
    const float* emb    = (const float*)d_in[3];
    const float* gW     = (const float*)d_in[4];
    const float* gb     = (const float*)d_in[5];
    const float* Wih0   = (const float*)d_in[6];
    const float* Whh0   = (const float*)d_in[7];
    const float* bih0   = (const float*)d_in[8];
    const float* bhh0   = (const float*)d_in[9];
    const float* Wih1   = (const float*)d_in[10];
    const float* Whh1   = (const float*)d_in[11];
    const float* bih1   = (const float*)d_in[12];
    const float* bhh1   = (const float*)d_in[13];
    const float* fcW    = (const float*)d_in[14];
    const float* fcb    = (const float*)d_in[15];
    const float* h0     = (const float*)d_in[16];  // (2, 200, 128)
    const float* c0     = (const float*)d_in[17];

    char* ws = (char*)d_ws;
    int*      deg_out = (int*)(ws + 0);          // 12800 ints
    int*      degr    = (int*)(ws + 51200);      // 64 ints
    int*      ecount  = (int*)(ws + 51456);      // 1 int
    float*    agg64   = (float*)(ws + 51712);    // 64*128 -> zero region ends at 84480
    int2*     elist   = (int2*)(ws + 84480);     // CAP entries (64 KB) -> 150016
    float*    h64     = (float*)(ws + 150016);   // 32 KB -> 182784
    float*    Gpre    = (float*)(ws + 182784);   // 128 KB -> 313856 (shared by both layers)
    float*    h1out   = (float*)(ws + 313856);   // 32 KB -> 346624
    float*    out64   = (float*)(ws + 346624);   // 32 KB -> 379392
    _Float16* AH      = (_Float16*)(ws + 379392);// 16 KB -> 395776
    _Float16* AL      = (_Float16*)(ws + 395776);// 16 KB -> 412160
    float*    logits  = (float*)d_out;

    hipMemsetAsync(ws, 0, 84480, stream);     // deg_out, degr, ecount, agg64

    k_deg_filter<<<E / 256, 256, 0, stream>>>(src, dst, deg_out, degr, ecount, elist);
    k_agg<<<CAP / 2, 256, 0, stream>>>(elist, ecount, gnodes, emb, deg_out, agg64);
    k_h64<<<1, 512, 0, stream>>>(agg64, degr, gW, gb, h64);

    k_gemmG<<<8, 256, 0, stream>>>(h64, Wih0, bih0, bhh0, Gpre);
    k_lstm<<<1, 512, 0, stream>>>(Whh0, Gpre, h0 + 199 * 128, c0 + 199 * 128, h1out);
    k_gemmG<<<8, 256, 0, stream>>>(h1out, Wih1, bih1, bhh1, Gpre);
    k_lstm<<<1, 512, 0, stream>>>(Whh1, Gpre, h0 + (200 + 199) * 128, c0 + (200 + 199) * 128, out64);

    k_splitA<<<1, 512, 0, stream>>>(out64, AH, AL);
    // ceil(ceil(V/16)/8) = 1001 blocks: covers all 8001 v-tiles incl. v=128000
    k_fc<<<1001, 256, 0, stream>>>(AH, AL, fcW, fcb, logits);
}